// Round 1
// baseline (10546.901 us; speedup 1.0000x reference)
//
#include <hip/hip_runtime.h>
#include <hip/hip_bf16.h>
#include <math.h>

// Problem constants
#define BB 64
#define TT 256
#define EE 300
#define DD 600
#define HH 512
#define G4 2048   // 4*H
#define LL 9
#define NT (BB*TT)        // 16384 tokens
#define BH (BB*HH)        // 32768 floats per h/c buffer

// Workspace layout (bytes)
#define XZF_OFF 0
#define XZ_BYTES ((size_t)NT * G4 * 2)            // bf16: 67108864
#define XZB_OFF (XZF_OFF + XZ_BYTES)
#define HSF_OFF (XZB_OFF + XZ_BYTES)
#define HS_BYTES ((size_t)NT * HH * 2)            // bf16: 16777216
#define HSB_OFF (HSF_OFF + HS_BYTES)
#define HC_OFF  (HSB_OFF + HS_BYTES)
#define HC_BYTES ((size_t)6 * BH * 4)             // hA,hB,c per dir
#define BP_OFF  (HC_OFF + HC_BYTES)
#define BP_BYTES ((size_t)BB * (TT-1) * LL * 4)
#define LEN_OFF (BP_OFF + BP_BYTES)

// Output layout (floats)
#define OUT_LOGITS 0
#define OUT_LENS   (BB*TT*LL)            // 147456
#define OUT_LL     (OUT_LENS + BB)       // 147520
#define OUT_TAGS   (OUT_LL + BB)         // 147584

// ---------------------------------------------------------------------------
// Kernel 1: embedding gather + x @ Wk + b  -> xz (bf16), both directions
// ---------------------------------------------------------------------------
__global__ __launch_bounds__(256) void embed_xz(
    const int* __restrict__ text, const int* __restrict__ sent,
    const float* __restrict__ wemb, const float* __restrict__ semb,
    const float* __restrict__ Wk_f, const float* __restrict__ b_f,
    const float* __restrict__ Wk_b, const float* __restrict__ b_b,
    __hip_bfloat16* __restrict__ xz_f, __hip_bfloat16* __restrict__ xz_b)
{
    int dir = blockIdx.z;
    const float* Wk   = dir ? Wk_b : Wk_f;
    const float* bias = dir ? b_b  : b_f;
    __hip_bfloat16* out = dir ? xz_b : xz_f;

    int n0 = blockIdx.x * 64;
    int c0 = blockIdx.y * 64;
    int tid = threadIdx.x;
    int tx = tid & 15, ty = tid >> 4;

    __shared__ float As[16][65];   // [k][row]
    __shared__ float Bs[16][64];   // [k][col]
    float acc[4][4] = {};

    for (int kt = 0; kt < DD; kt += 16) {
        // Load A tile: 64 rows x 16 k (gathered from embeddings)
        #pragma unroll
        for (int r = 0; r < 4; ++r) {
            int idx = tid + r * 256;
            int rr = idx >> 4, kk = idx & 15;
            int d = kt + kk;
            int n = n0 + rr;
            float v = 0.f;
            if (d < DD) {
                v = (d < EE) ? wemb[(size_t)text[n] * EE + d]
                             : semb[(size_t)sent[n] * EE + (d - EE)];
            }
            As[kk][rr] = v;
        }
        // Load B tile: 16 k x 64 cols
        #pragma unroll
        for (int r = 0; r < 4; ++r) {
            int idx = tid + r * 256;
            int kk = idx >> 6, cc = idx & 63;
            int d = kt + kk;
            Bs[kk][cc] = (d < DD) ? Wk[(size_t)d * G4 + c0 + cc] : 0.f;
        }
        __syncthreads();
        #pragma unroll
        for (int k = 0; k < 16; ++k) {
            float a[4], b[4];
            #pragma unroll
            for (int i = 0; i < 4; ++i) a[i] = As[k][ty*4+i];
            #pragma unroll
            for (int j = 0; j < 4; ++j) b[j] = Bs[k][tx*4+j];
            #pragma unroll
            for (int i = 0; i < 4; ++i)
                #pragma unroll
                for (int j = 0; j < 4; ++j)
                    acc[i][j] += a[i] * b[j];
        }
        __syncthreads();
    }
    #pragma unroll
    for (int i = 0; i < 4; ++i) {
        int n = n0 + ty*4 + i;
        #pragma unroll
        for (int j = 0; j < 4; ++j) {
            int cc = c0 + tx*4 + j;
            out[(size_t)n * G4 + cc] = __float2bfloat16(acc[i][j] + bias[cc]);
        }
    }
}

// ---------------------------------------------------------------------------
// Kernel 2: one LSTM time step, both directions.
// grid (32 hid-blocks, 4 row-blocks, 2 dirs), block 256 = 16 hid x 16 rows
// ---------------------------------------------------------------------------
__global__ __launch_bounds__(256) void lstm_step(
    const __hip_bfloat16* __restrict__ xz_f, const __hip_bfloat16* __restrict__ xz_b,
    const float* __restrict__ Wr_f, const float* __restrict__ Wr_b,
    float* __restrict__ hc,
    __hip_bfloat16* __restrict__ hs_f, __hip_bfloat16* __restrict__ hs_b,
    int t)
{
    int dir = blockIdx.z;
    const __hip_bfloat16* xz = dir ? xz_b : xz_f;
    const float* Wr = dir ? Wr_b : Wr_f;
    __hip_bfloat16* hs = dir ? hs_b : hs_f;
    float* base = hc + (size_t)dir * 3 * BH;
    const float* h_in  = base + (size_t)(t & 1) * BH;
    float*       h_out = base + (size_t)((t + 1) & 1) * BH;
    float*       c     = base + (size_t)2 * BH;
    int tok = dir ? (TT - 1 - t) : t;

    int tid = threadIdx.x;
    int tx = tid & 15, ty = tid >> 4;
    int r0 = blockIdx.y * 16;
    int row = r0 + ty;
    int hid = blockIdx.x * 16 + tx;

    __shared__ float hsld[16][513];
    for (int i = tid; i < 16 * HH; i += 256)
        hsld[i >> 9][i & 511] = h_in[(size_t)(r0 + (i >> 9)) * HH + (i & 511)];
    __syncthreads();

    float acc0 = 0.f, acc1 = 0.f, acc2 = 0.f, acc3 = 0.f;
    const float* wr = Wr + hid;
    #pragma unroll 4
    for (int k = 0; k < HH; ++k) {
        float hk = hsld[ty][k];
        const float* w = wr + (size_t)k * G4;
        acc0 += hk * w[0];
        acc1 += hk * w[512];
        acc2 += hk * w[1024];
        acc3 += hk * w[1536];
    }

    const __hip_bfloat16* xzp = xz + (size_t)(row * TT + tok) * G4 + hid;
    float zi = acc0 + __bfloat162float(xzp[0]);
    float zf = acc1 + __bfloat162float(xzp[512]);
    float zg = acc2 + __bfloat162float(xzp[1024]);
    float zo = acc3 + __bfloat162float(xzp[1536]);

    float si = 1.f / (1.f + __expf(-zi));
    float sf = 1.f / (1.f + __expf(-zf));
    float so = 1.f / (1.f + __expf(-zo));
    float cprev = c[(size_t)row * HH + hid];
    float cn = sf * cprev + si * tanhf(zg);
    float hn = so * tanhf(cn);
    c[(size_t)row * HH + hid] = cn;
    h_out[(size_t)row * HH + hid] = hn;
    hs[(size_t)(row * TT + tok) * HH + hid] = __float2bfloat16(hn);
}

// ---------------------------------------------------------------------------
// Kernel 3: logits = [hf, hb] @ Wd + bd    (one block of 64 threads per token)
// ---------------------------------------------------------------------------
__global__ __launch_bounds__(64) void logits_kernel(
    const __hip_bfloat16* __restrict__ hs_f, const __hip_bfloat16* __restrict__ hs_b,
    const float* __restrict__ Wd, const float* __restrict__ bd,
    float* __restrict__ out)
{
    int n = blockIdx.x;
    int tid = threadIdx.x;
    __shared__ float red[64][10];
    float acc[LL] = {};
    for (int kk = 0; kk < 16; ++kk) {
        int k = kk * 64 + tid;
        float hv = (k < HH) ? __bfloat162float(hs_f[(size_t)n * HH + k])
                            : __bfloat162float(hs_b[(size_t)n * HH + (k - HH)]);
        const float* w = Wd + (size_t)k * LL;
        #pragma unroll
        for (int l = 0; l < LL; ++l) acc[l] += hv * w[l];
    }
    #pragma unroll
    for (int l = 0; l < LL; ++l) red[tid][l] = acc[l];
    __syncthreads();
    for (int s = 32; s > 0; s >>= 1) {
        if (tid < s)
            for (int l = 0; l < LL; ++l) red[tid][l] += red[tid + s][l];
        __syncthreads();
    }
    if (tid < LL) out[(size_t)n * LL + tid] = red[0][tid] + bd[tid];
}

// ---------------------------------------------------------------------------
// Kernel 4: text lengths
// ---------------------------------------------------------------------------
__global__ __launch_bounds__(256) void lens_kernel(
    const int* __restrict__ text, float* __restrict__ out_lens, int* __restrict__ len_i)
{
    int b = blockIdx.x, tid = threadIdx.x;
    __shared__ int sred[256];
    sred[tid] = (text[b * TT + tid] != 0) ? 1 : 0;
    __syncthreads();
    for (int s = 128; s > 0; s >>= 1) {
        if (tid < s) sred[tid] += sred[tid + s];
        __syncthreads();
    }
    if (tid == 0) { out_lens[b] = (float)sred[0]; len_i[b] = sred[0]; }
}

// ---------------------------------------------------------------------------
// Kernel 5: CRF log-likelihood + Viterbi decode (one block per batch item)
// ---------------------------------------------------------------------------
__global__ __launch_bounds__(128) void crf_kernel(
    const float* __restrict__ logits, const int* __restrict__ labels,
    const float* __restrict__ trans, const int* __restrict__ len_i,
    int* __restrict__ bp, float* __restrict__ out_ll, float* __restrict__ out_tags)
{
    int b = blockIdx.x, tid = threadIdx.x;
    int len = len_i[b];
    const float* lg = logits + (size_t)b * TT * LL;
    const int* lab = labels + b * TT;

    __shared__ float tr[81];
    __shared__ float alpha[LL], vit[LL], newa[LL], newv[LL];
    __shared__ int newbp[LL];
    __shared__ float partial[128];

    if (tid < 81) tr[tid] = trans[tid];
    if (tid < LL) { alpha[tid] = lg[tid]; vit[tid] = lg[tid]; }

    // unary + binary
    float up = 0.f;
    for (int t = tid; t < TT; t += 128) {
        float m = (t < len) ? 1.f : 0.f;
        up += m * lg[t * LL + lab[t]];
        if (t >= 1) up += m * tr[lab[t - 1] * LL + lab[t]];
    }
    // note: tr not yet synced for threads >=81? tid<81 wrote own tr; need sync first.
    __syncthreads();
    // recompute binary part safely after sync (cheap): redo whole partial
    up = 0.f;
    for (int t = tid; t < TT; t += 128) {
        float m = (t < len) ? 1.f : 0.f;
        up += m * lg[t * LL + lab[t]];
        if (t >= 1) up += m * tr[lab[t - 1] * LL + lab[t]];
    }
    partial[tid] = up;
    __syncthreads();
    for (int s = 64; s > 0; s >>= 1) {
        if (tid < s) partial[tid] += partial[tid + s];
        __syncthreads();
    }

    // recursions: threads 0..8 = logsumexp alpha; threads 64..72 = viterbi
    for (int t = 1; t < TT; ++t) {
        bool m = t < len;
        if (tid < LL) {
            int j = tid;
            float mx = -1e30f;
            #pragma unroll
            for (int i = 0; i < LL; ++i) mx = fmaxf(mx, alpha[i] + tr[i * LL + j]);
            float s = 0.f;
            #pragma unroll
            for (int i = 0; i < LL; ++i) s += __expf(alpha[i] + tr[i * LL + j] - mx);
            newa[j] = mx + __logf(s) + lg[t * LL + j];
        } else if (tid >= 64 && tid < 64 + LL) {
            int j = tid - 64;
            float best = -1e30f; int bi = 0;
            #pragma unroll
            for (int i = 0; i < LL; ++i) {
                float sc = vit[i] + tr[i * LL + j];
                if (sc > best) { best = sc; bi = i; }
            }
            newv[j] = best + lg[t * LL + j];
            newbp[j] = bi;
        }
        __syncthreads();
        if (tid < LL) {
            if (m) alpha[tid] = newa[tid];
        } else if (tid >= 64 && tid < 64 + LL) {
            int j = tid - 64;
            if (m) vit[j] = newv[j];
            bp[((size_t)b * (TT - 1) + (t - 1)) * LL + j] = m ? newbp[j] : j;
        }
        __syncthreads();
    }

    if (tid == 0) {
        float mx = -1e30f;
        #pragma unroll
        for (int j = 0; j < LL; ++j) mx = fmaxf(mx, alpha[j]);
        float s = 0.f;
        #pragma unroll
        for (int j = 0; j < LL; ++j) s += __expf(alpha[j] - mx);
        float log_norm = mx + __logf(s);
        out_ll[b] = partial[0] - log_norm;

        float bv = vit[0]; int last = 0;
        #pragma unroll
        for (int j = 1; j < LL; ++j) if (vit[j] > bv) { bv = vit[j]; last = j; }
        out_tags[b * TT + (TT - 1)] = (float)last;
        int tag = last;
        for (int s2 = TT - 2; s2 >= 0; --s2) {
            tag = bp[((size_t)b * (TT - 1) + s2) * LL + tag];
            out_tags[b * TT + s2] = (float)tag;
        }
    }
}

// ---------------------------------------------------------------------------
extern "C" void kernel_launch(void* const* d_in, const int* in_sizes, int n_in,
                              void* d_out, int out_size, void* d_ws, size_t ws_size,
                              hipStream_t stream)
{
    const int*   text  = (const int*)d_in[0];
    const int*   sent  = (const int*)d_in[1];
    const int*   labels= (const int*)d_in[2];
    const float* wemb  = (const float*)d_in[3];
    const float* semb  = (const float*)d_in[4];
    const float* Wk_f  = (const float*)d_in[5];
    const float* Wr_f  = (const float*)d_in[6];
    const float* b_f   = (const float*)d_in[7];
    const float* Wk_b  = (const float*)d_in[8];
    const float* Wr_b  = (const float*)d_in[9];
    const float* b_b   = (const float*)d_in[10];
    const float* Wd    = (const float*)d_in[11];
    const float* bd    = (const float*)d_in[12];
    const float* trans = (const float*)d_in[13];
    float* out = (float*)d_out;

    char* ws = (char*)d_ws;
    __hip_bfloat16* xz_f = (__hip_bfloat16*)(ws + XZF_OFF);
    __hip_bfloat16* xz_b = (__hip_bfloat16*)(ws + XZB_OFF);
    __hip_bfloat16* hs_f = (__hip_bfloat16*)(ws + HSF_OFF);
    __hip_bfloat16* hs_b = (__hip_bfloat16*)(ws + HSB_OFF);
    float* hc   = (float*)(ws + HC_OFF);
    int*   bp   = (int*)(ws + BP_OFF);
    int*   leni = (int*)(ws + LEN_OFF);

    hipMemsetAsync(ws + HC_OFF, 0, HC_BYTES, stream);

    embed_xz<<<dim3(NT/64, G4/64, 2), 256, 0, stream>>>(
        text, sent, wemb, semb, Wk_f, b_f, Wk_b, b_b, xz_f, xz_b);

    for (int t = 0; t < TT; ++t) {
        lstm_step<<<dim3(HH/16, BB/16, 2), 256, 0, stream>>>(
            xz_f, xz_b, Wr_f, Wr_b, hc, hs_f, hs_b, t);
    }

    logits_kernel<<<NT, 64, 0, stream>>>(hs_f, hs_b, Wd, bd, out + OUT_LOGITS);
    lens_kernel<<<BB, 256, 0, stream>>>(text, out + OUT_LENS, leni);
    crf_kernel<<<BB, 128, 0, stream>>>(out + OUT_LOGITS, labels, trans, leni,
                                       bp, out + OUT_LL, out + OUT_TAGS);
}

// Round 2
// 9020.132 us; speedup vs baseline: 1.1693x; 1.1693x over previous
//
#include <hip/hip_runtime.h>
#include <hip/hip_bf16.h>
#include <hip/hip_cooperative_groups.h>
#include <math.h>

namespace cg = cooperative_groups;

// Problem constants
#define BB 64
#define TT 256
#define EE 300
#define DD 600
#define KP 608        // K padded to 19*32 for MFMA
#define HH 512
#define G4 2048
#define LL 9
#define NT (BB*TT)

typedef __attribute__((ext_vector_type(8))) short short8;   // 8 bf16
typedef __attribute__((ext_vector_type(4))) float floatx4;  // MFMA acc

// ---------------- Workspace layout (bytes) ----------------
#define XZF_OFF  ((size_t)0)
#define XZ_BYTES ((size_t)NT * G4 * 2)                  // 67108864
#define XZB_OFF  (XZF_OFF + XZ_BYTES)
#define HSR_OFF  (XZB_OFF + XZ_BYTES)                   // hs region, 33554432
#define HS_BYTES ((size_t)NT * HH * 2)                  // 16777216
#define HSF_OFF  (HSR_OFF)
#define HSB_OFF  (HSR_OFF + HS_BYTES)
// aliases inside hs region (dead before their overwriters run):
#define XG_OFF   (HSR_OFF)                              // 16384*608*2 = 19922944 (dead before lstm)
#define WKT_OFF  (HSR_OFF + 19922944)                   // 2*2048*608*2 = 4980736 (dead before lstm)
#define BP_OFF   (HSR_OFF + 25165824)                   // 64*255*9*4 = 587520 (written after logits reads hs)
#define WRT_OFF  (HSR_OFF + (size_t)2 * HS_BYTES)       // 2*2048*512*2 = 4194304
#define HB_OFF   (WRT_OFF + 4194304)                    // 2dir*2par*64*512*2 = 262144
#define HB_BYTES ((size_t)262144)
#define LEN_OFF  (HB_OFF + HB_BYTES)

// Output layout (floats)
#define OUT_LOGITS 0
#define OUT_LENS   (BB*TT*LL)
#define OUT_LL     (OUT_LENS + BB)
#define OUT_TAGS   (OUT_LL + BB)

// ---------------------------------------------------------------------------
// Prep 1: gather embeddings -> xg[n][608] bf16 (zero-padded K)
// ---------------------------------------------------------------------------
__global__ __launch_bounds__(256) void prep_xg(
    const int* __restrict__ text, const int* __restrict__ sent,
    const float* __restrict__ wemb, const float* __restrict__ semb,
    __hip_bfloat16* __restrict__ xg)
{
    int n = blockIdx.x;
    int ti = text[n], si = sent[n];
    __hip_bfloat16* o = xg + (size_t)n * KP;
    for (int k = threadIdx.x; k < KP; k += 256) {
        float v = 0.f;
        if (k < EE)      v = wemb[(size_t)ti * EE + k];
        else if (k < DD) v = semb[(size_t)si * EE + (k - EE)];
        o[k] = __float2bfloat16(v);
    }
}

// ---------------------------------------------------------------------------
// Prep 2: WkT[dir][n][k] bf16 (transposed, zero-padded to 608)
// ---------------------------------------------------------------------------
__global__ __launch_bounds__(256) void prep_wkT(
    const float* __restrict__ Wk_f, const float* __restrict__ Wk_b,
    __hip_bfloat16* __restrict__ WkT)
{
    int n = blockIdx.x, dir = blockIdx.y;
    const float* Wk = dir ? Wk_b : Wk_f;
    __hip_bfloat16* o = WkT + (size_t)dir * G4 * KP + (size_t)n * KP;
    for (int k = threadIdx.x; k < KP; k += 256)
        o[k] = __float2bfloat16(k < DD ? Wk[(size_t)k * G4 + n] : 0.f);
}

// ---------------------------------------------------------------------------
// Prep 3: WrT[dir][n][k] bf16 (transposed, K=512 exact)
// ---------------------------------------------------------------------------
__global__ __launch_bounds__(256) void prep_wrT(
    const float* __restrict__ Wr_f, const float* __restrict__ Wr_b,
    __hip_bfloat16* __restrict__ WrT)
{
    int n = blockIdx.x, dir = blockIdx.y;
    const float* Wr = dir ? Wr_b : Wr_f;
    __hip_bfloat16* o = WrT + (size_t)dir * G4 * HH + (size_t)n * HH;
    for (int k = threadIdx.x; k < HH; k += 256)
        o[k] = __float2bfloat16(Wr[(size_t)k * G4 + n]);
}

// ---------------------------------------------------------------------------
// Embed GEMM: xz[dir][n][col] = xg @ Wk + b   (bf16 MFMA, frags from L2)
// grid (256 m-blocks, 32 n-blocks, 2 dirs), block 256 = 4 waves, tile 64x64
// ---------------------------------------------------------------------------
__global__ __launch_bounds__(256) void embed_gemm(
    const __hip_bfloat16* __restrict__ xg,
    const __hip_bfloat16* __restrict__ WkT,
    const float* __restrict__ b_f, const float* __restrict__ b_b,
    __hip_bfloat16* __restrict__ xz_f, __hip_bfloat16* __restrict__ xz_b)
{
    int dir = blockIdx.z;
    const __hip_bfloat16* wt = WkT + (size_t)dir * G4 * KP;
    const float* bias = dir ? b_b : b_f;
    __hip_bfloat16* xz = dir ? xz_b : xz_f;

    int n0 = blockIdx.x * 64;    // token rows
    int c0 = blockIdx.y * 64;    // output cols
    int wave = threadIdx.x >> 6, lane = threadIdx.x & 63;
    int mt2 = (wave & 1) * 2;    // this wave's 2 m-tiles
    int nt2 = (wave >> 1) * 2;   // this wave's 2 n-tiles
    int lm = lane & 15, lk8 = (lane >> 4) * 8;

    const short8* ap[2], *bp[2];
    ap[0] = (const short8*)(xg + (size_t)(n0 + (mt2+0)*16 + lm) * KP + lk8);
    ap[1] = (const short8*)(xg + (size_t)(n0 + (mt2+1)*16 + lm) * KP + lk8);
    bp[0] = (const short8*)(wt + (size_t)(c0 + (nt2+0)*16 + lm) * KP + lk8);
    bp[1] = (const short8*)(wt + (size_t)(c0 + (nt2+1)*16 + lm) * KP + lk8);

    floatx4 acc[2][2] = {};
    for (int kc = 0; kc < KP/32; ++kc) {
        short8 a0 = ap[0][kc*4];
        short8 a1 = ap[1][kc*4];
        short8 b0 = bp[0][kc*4];
        short8 b1 = bp[1][kc*4];
        acc[0][0] = __builtin_amdgcn_mfma_f32_16x16x32_bf16(a0, b0, acc[0][0], 0,0,0);
        acc[0][1] = __builtin_amdgcn_mfma_f32_16x16x32_bf16(a0, b1, acc[0][1], 0,0,0);
        acc[1][0] = __builtin_amdgcn_mfma_f32_16x16x32_bf16(a1, b0, acc[1][0], 0,0,0);
        acc[1][1] = __builtin_amdgcn_mfma_f32_16x16x32_bf16(a1, b1, acc[1][1], 0,0,0);
    }

    float bias0 = bias[c0 + (nt2+0)*16 + lm];
    float bias1 = bias[c0 + (nt2+1)*16 + lm];
    int lr = (lane >> 4) * 4;
    #pragma unroll
    for (int mi = 0; mi < 2; ++mi)
        #pragma unroll
        for (int ni = 0; ni < 2; ++ni) {
            int col = c0 + (nt2+ni)*16 + lm;
            float bs = ni ? bias1 : bias0;
            #pragma unroll
            for (int r = 0; r < 4; ++r) {
                int row = n0 + (mt2+mi)*16 + lr + r;
                xz[(size_t)row * G4 + col] = __float2bfloat16(acc[mi][ni][r] + bs);
            }
        }
}

// ---------------------------------------------------------------------------
// Persistent cooperative LSTM. 256 blocks (1/CU) x 256 threads.
// block = (dir, rowgroup of 16, hgroup of 16). wave = gate. Wr slice lives in
// VGPRs (16 bf16x8 frags) for all 256 steps. h ping-pongs in global bf16.
// ---------------------------------------------------------------------------
__global__ __launch_bounds__(256, 1) void lstm_coop(
    const __hip_bfloat16* __restrict__ xz_f, const __hip_bfloat16* __restrict__ xz_b,
    const __hip_bfloat16* __restrict__ WrT,   // [2][2048][512]
    __hip_bfloat16* __restrict__ hb,          // [2dir][2par][64][512]
    __hip_bfloat16* __restrict__ hs_f, __hip_bfloat16* __restrict__ hs_b)
{
    cg::grid_group grid = cg::this_grid();

    int blk = blockIdx.x;
    int dir = blk >> 7, sub = blk & 127;
    int r0 = (sub >> 5) * 16;     // 4 rowgroups
    int h0 = (sub & 31) * 16;     // 32 hgroups
    int tid = threadIdx.x;
    int gate = tid >> 6, lane = tid & 63;
    int lm = lane & 15, lk8 = (lane >> 4) * 8;

    const __hip_bfloat16* xz = dir ? xz_b : xz_f;
    __hip_bfloat16* hs = dir ? hs_b : hs_f;
    const __hip_bfloat16* wrt = WrT + (size_t)dir * G4 * HH;
    __hip_bfloat16* hbd = hb + (size_t)dir * 2 * BB * HH;

    // persistent weight fragments (gate's 16 cols x full K=512)
    short8 bfrag[16];
    {
        const short8* wp = (const short8*)(wrt + (size_t)(gate*HH + h0 + lm) * HH + lk8);
        #pragma unroll
        for (int kc = 0; kc < 16; ++kc) bfrag[kc] = wp[kc*4];
    }

    __shared__ float zbuf[4][16][17];

    int er = tid >> 4, eh = tid & 15;   // epilogue (row, hid)
    float cst = 0.f;                    // cell state, fp32, in-register

    for (int t = 0; t < TT; ++t) {
        int tok = dir ? (TT - 1 - t) : t;
        const short8* hp = (const short8*)(hbd + (size_t)(t & 1) * BB * HH
                                               + (size_t)(r0 + lm) * HH + lk8);
        floatx4 acc = {};
        #pragma unroll
        for (int kc = 0; kc < 16; ++kc)
            acc = __builtin_amdgcn_mfma_f32_16x16x32_bf16(hp[kc*4], bfrag[kc], acc, 0,0,0);

        // add xz (bias folded in), publish z-tile to LDS for gate exchange
        #pragma unroll
        for (int r = 0; r < 4; ++r) {
            int row = (lane >> 4) * 4 + r;
            int n = (r0 + row) * TT + tok;
            float z = acc[r] + __bfloat162float(xz[(size_t)n * G4 + gate*HH + h0 + lm]);
            zbuf[gate][row][lm] = z;
        }
        __syncthreads();

        float zi = zbuf[0][er][eh], zf = zbuf[1][er][eh];
        float zg = zbuf[2][er][eh], zo = zbuf[3][er][eh];
        float si = 1.f / (1.f + __expf(-zi));
        float sf = 1.f / (1.f + __expf(-zf));
        float so = 1.f / (1.f + __expf(-zo));
        cst = sf * cst + si * tanhf(zg);
        float hn = so * tanhf(cst);
        __hip_bfloat16 hbf = __float2bfloat16(hn);
        hbd[(size_t)((t+1) & 1) * BB * HH + (size_t)(r0 + er) * HH + h0 + eh] = hbf;
        hs[((size_t)(r0 + er) * TT + tok) * HH + h0 + eh] = hbf;

        grid.sync();   // h published device-wide; also protects zbuf reuse
    }
}

// ---------------------------------------------------------------------------
// logits = [hf, hb] @ Wd + bd
// ---------------------------------------------------------------------------
__global__ __launch_bounds__(64) void logits_kernel(
    const __hip_bfloat16* __restrict__ hs_f, const __hip_bfloat16* __restrict__ hs_b,
    const float* __restrict__ Wd, const float* __restrict__ bd,
    float* __restrict__ out)
{
    int n = blockIdx.x;
    int tid = threadIdx.x;
    __shared__ float red[64][10];
    float acc[LL] = {};
    for (int kk = 0; kk < 16; ++kk) {
        int k = kk * 64 + tid;
        float hv = (k < HH) ? __bfloat162float(hs_f[(size_t)n * HH + k])
                            : __bfloat162float(hs_b[(size_t)n * HH + (k - HH)]);
        const float* w = Wd + (size_t)k * LL;
        #pragma unroll
        for (int l = 0; l < LL; ++l) acc[l] += hv * w[l];
    }
    #pragma unroll
    for (int l = 0; l < LL; ++l) red[tid][l] = acc[l];
    __syncthreads();
    for (int s = 32; s > 0; s >>= 1) {
        if (tid < s)
            for (int l = 0; l < LL; ++l) red[tid][l] += red[tid + s][l];
        __syncthreads();
    }
    if (tid < LL) out[(size_t)n * LL + tid] = red[0][tid] + bd[tid];
}

// ---------------------------------------------------------------------------
// text lengths
// ---------------------------------------------------------------------------
__global__ __launch_bounds__(256) void lens_kernel(
    const int* __restrict__ text, float* __restrict__ out_lens, int* __restrict__ len_i)
{
    int b = blockIdx.x, tid = threadIdx.x;
    __shared__ int sred[256];
    sred[tid] = (text[b * TT + tid] != 0) ? 1 : 0;
    __syncthreads();
    for (int s = 128; s > 0; s >>= 1) {
        if (tid < s) sred[tid] += sred[tid + s];
        __syncthreads();
    }
    if (tid == 0) { out_lens[b] = (float)sred[0]; len_i[b] = sred[0]; }
}

// ---------------------------------------------------------------------------
// CRF log-likelihood + Viterbi decode (one block per batch item)
// ---------------------------------------------------------------------------
__global__ __launch_bounds__(128) void crf_kernel(
    const float* __restrict__ logits, const int* __restrict__ labels,
    const float* __restrict__ trans, const int* __restrict__ len_i,
    int* __restrict__ bp, float* __restrict__ out_ll, float* __restrict__ out_tags)
{
    int b = blockIdx.x, tid = threadIdx.x;
    int len = len_i[b];
    const float* lg = logits + (size_t)b * TT * LL;
    const int* lab = labels + b * TT;

    __shared__ float tr[81];
    __shared__ float alpha[LL], vit[LL], newa[LL], newv[LL];
    __shared__ int newbp[LL];
    __shared__ float partial[128];

    if (tid < 81) tr[tid] = trans[tid];
    if (tid < LL) { alpha[tid] = lg[tid]; vit[tid] = lg[tid]; }
    __syncthreads();

    float up = 0.f;
    for (int t = tid; t < TT; t += 128) {
        float m = (t < len) ? 1.f : 0.f;
        up += m * lg[t * LL + lab[t]];
        if (t >= 1) up += m * tr[lab[t - 1] * LL + lab[t]];
    }
    partial[tid] = up;
    __syncthreads();
    for (int s = 64; s > 0; s >>= 1) {
        if (tid < s) partial[tid] += partial[tid + s];
        __syncthreads();
    }

    for (int t = 1; t < TT; ++t) {
        bool m = t < len;
        if (tid < LL) {
            int j = tid;
            float mx = -1e30f;
            #pragma unroll
            for (int i = 0; i < LL; ++i) mx = fmaxf(mx, alpha[i] + tr[i * LL + j]);
            float s = 0.f;
            #pragma unroll
            for (int i = 0; i < LL; ++i) s += __expf(alpha[i] + tr[i * LL + j] - mx);
            newa[j] = mx + __logf(s) + lg[t * LL + j];
        } else if (tid >= 64 && tid < 64 + LL) {
            int j = tid - 64;
            float best = -1e30f; int bi = 0;
            #pragma unroll
            for (int i = 0; i < LL; ++i) {
                float sc = vit[i] + tr[i * LL + j];
                if (sc > best) { best = sc; bi = i; }
            }
            newv[j] = best + lg[t * LL + j];
            newbp[j] = bi;
        }
        __syncthreads();
        if (tid < LL) {
            if (m) alpha[tid] = newa[tid];
        } else if (tid >= 64 && tid < 64 + LL) {
            int j = tid - 64;
            if (m) vit[j] = newv[j];
            bp[((size_t)b * (TT - 1) + (t - 1)) * LL + j] = m ? newbp[j] : j;
        }
        __syncthreads();
    }

    if (tid == 0) {
        float mx = -1e30f;
        #pragma unroll
        for (int j = 0; j < LL; ++j) mx = fmaxf(mx, alpha[j]);
        float s = 0.f;
        #pragma unroll
        for (int j = 0; j < LL; ++j) s += __expf(alpha[j] - mx);
        out_ll[b] = partial[0] - (mx + __logf(s));

        float bv = vit[0]; int last = 0;
        #pragma unroll
        for (int j = 1; j < LL; ++j) if (vit[j] > bv) { bv = vit[j]; last = j; }
        out_tags[b * TT + (TT - 1)] = (float)last;
        int tag = last;
        for (int s2 = TT - 2; s2 >= 0; --s2) {
            tag = bp[((size_t)b * (TT - 1) + s2) * LL + tag];
            out_tags[b * TT + s2] = (float)tag;
        }
    }
}

// ---------------------------------------------------------------------------
extern "C" void kernel_launch(void* const* d_in, const int* in_sizes, int n_in,
                              void* d_out, int out_size, void* d_ws, size_t ws_size,
                              hipStream_t stream)
{
    const int*   text  = (const int*)d_in[0];
    const int*   sent  = (const int*)d_in[1];
    const int*   labels= (const int*)d_in[2];
    const float* wemb  = (const float*)d_in[3];
    const float* semb  = (const float*)d_in[4];
    const float* Wk_f  = (const float*)d_in[5];
    const float* Wr_f  = (const float*)d_in[6];
    const float* b_f   = (const float*)d_in[7];
    const float* Wk_b  = (const float*)d_in[8];
    const float* Wr_b  = (const float*)d_in[9];
    const float* b_b   = (const float*)d_in[10];
    const float* Wd    = (const float*)d_in[11];
    const float* bd    = (const float*)d_in[12];
    const float* trans = (const float*)d_in[13];
    float* out = (float*)d_out;

    char* ws = (char*)d_ws;
    __hip_bfloat16* xz_f = (__hip_bfloat16*)(ws + XZF_OFF);
    __hip_bfloat16* xz_b = (__hip_bfloat16*)(ws + XZB_OFF);
    __hip_bfloat16* hs_f = (__hip_bfloat16*)(ws + HSF_OFF);
    __hip_bfloat16* hs_b = (__hip_bfloat16*)(ws + HSB_OFF);
    __hip_bfloat16* xg   = (__hip_bfloat16*)(ws + XG_OFF);
    __hip_bfloat16* WkT  = (__hip_bfloat16*)(ws + WKT_OFF);
    __hip_bfloat16* WrT  = (__hip_bfloat16*)(ws + WRT_OFF);
    __hip_bfloat16* hb   = (__hip_bfloat16*)(ws + HB_OFF);
    int*   bp   = (int*)(ws + BP_OFF);
    int*   leni = (int*)(ws + LEN_OFF);

    // prep: gather + bf16 transposes (xg/WkT alias the hs region — dead
    // before lstm_coop starts writing hs)
    prep_xg <<<NT,  256, 0, stream>>>(text, sent, wemb, semb, xg);
    prep_wkT<<<dim3(G4, 2), 256, 0, stream>>>(Wk_f, Wk_b, WkT);
    prep_wrT<<<dim3(G4, 2), 256, 0, stream>>>(Wr_f, Wr_b, WrT);
    hipMemsetAsync(ws + HB_OFF, 0, HB_BYTES, stream);

    embed_gemm<<<dim3(NT/64, G4/64, 2), 256, 0, stream>>>(
        xg, WkT, b_f, b_b, xz_f, xz_b);

    {
        void* args[] = { (void*)&xz_f, (void*)&xz_b, (void*)&WrT,
                         (void*)&hb, (void*)&hs_f, (void*)&hs_b };
        hipLaunchCooperativeKernel((const void*)lstm_coop, dim3(256), dim3(256),
                                   args, 0, stream);
    }

    logits_kernel<<<NT, 64, 0, stream>>>(hs_f, hs_b, Wd, bd, out + OUT_LOGITS);
    lens_kernel<<<BB, 256, 0, stream>>>(text, out + OUT_LENS, leni);
    crf_kernel<<<BB, 128, 0, stream>>>(out + OUT_LOGITS, labels, trans, leni,
                                       bp, out + OUT_LL, out + OUT_TAGS);
}

// Round 3
// 1933.078 us; speedup vs baseline: 5.4560x; 4.6662x over previous
//
#include <hip/hip_runtime.h>
#include <hip/hip_bf16.h>
#include <math.h>

// Problem constants
#define BB 64
#define TT 256
#define EE 300
#define DD 600
#define KP 608        // K padded to 19*32 for MFMA
#define HH 512
#define G4 2048
#define LL 9
#define NT (BB*TT)

typedef __attribute__((ext_vector_type(8))) short short8;   // 8 bf16
typedef __attribute__((ext_vector_type(4))) float floatx4;  // MFMA acc

// ---------------- Workspace layout (bytes) ----------------
#define XZF_OFF  ((size_t)0)
#define XZ_BYTES ((size_t)NT * G4 * 2)                  // 67108864
#define XZB_OFF  (XZF_OFF + XZ_BYTES)
#define HSR_OFF  (XZB_OFF + XZ_BYTES)                   // hs region, 33554432
#define HS_BYTES ((size_t)NT * HH * 2)                  // 16777216
#define HSF_OFF  (HSR_OFF)
#define HSB_OFF  (HSR_OFF + HS_BYTES)
// aliases inside hs region (dead before their overwriters run):
#define XG_OFF   (HSR_OFF)                              // 16384*608*2 (dead before lstm)
#define WKT_OFF  (HSR_OFF + 19922944)                   // 2*2048*608*2 (dead before lstm)
#define BP_OFF   (HSR_OFF + 25165824)                   // written after logits reads hs
#define WRT_OFF  (HSR_OFF + (size_t)2 * HS_BYTES)       // 2*2048*512*2 = 4194304
#define HB_OFF   (WRT_OFF + 4194304)                    // 2dir*2par*64*512*2 = 262144
#define HB_BYTES ((size_t)262144)
#define LEN_OFF  (HB_OFF + HB_BYTES)
#define FLAGS_OFF (LEN_OFF + 256)                       // 8 groups * 32 uint

// Output layout (floats)
#define OUT_LOGITS 0
#define OUT_LENS   (BB*TT*LL)
#define OUT_LL     (OUT_LENS + BB)
#define OUT_TAGS   (OUT_LL + BB)

// ---------------------------------------------------------------------------
// Prep 1: gather embeddings -> xg[n][608] bf16 (zero-padded K)
// ---------------------------------------------------------------------------
__global__ __launch_bounds__(256) void prep_xg(
    const int* __restrict__ text, const int* __restrict__ sent,
    const float* __restrict__ wemb, const float* __restrict__ semb,
    __hip_bfloat16* __restrict__ xg)
{
    int n = blockIdx.x;
    int ti = text[n], si = sent[n];
    __hip_bfloat16* o = xg + (size_t)n * KP;
    for (int k = threadIdx.x; k < KP; k += 256) {
        float v = 0.f;
        if (k < EE)      v = wemb[(size_t)ti * EE + k];
        else if (k < DD) v = semb[(size_t)si * EE + (k - EE)];
        o[k] = __float2bfloat16(v);
    }
}

// ---------------------------------------------------------------------------
// Prep 2: WkT[dir][n][k] bf16 (transposed, zero-padded to 608)
// ---------------------------------------------------------------------------
__global__ __launch_bounds__(256) void prep_wkT(
    const float* __restrict__ Wk_f, const float* __restrict__ Wk_b,
    __hip_bfloat16* __restrict__ WkT)
{
    int n = blockIdx.x, dir = blockIdx.y;
    const float* Wk = dir ? Wk_b : Wk_f;
    __hip_bfloat16* o = WkT + (size_t)dir * G4 * KP + (size_t)n * KP;
    for (int k = threadIdx.x; k < KP; k += 256)
        o[k] = __float2bfloat16(k < DD ? Wk[(size_t)k * G4 + n] : 0.f);
}

// ---------------------------------------------------------------------------
// Prep 3: WrT[dir][n][k] bf16 (transposed, K=512 exact)
// ---------------------------------------------------------------------------
__global__ __launch_bounds__(256) void prep_wrT(
    const float* __restrict__ Wr_f, const float* __restrict__ Wr_b,
    __hip_bfloat16* __restrict__ WrT)
{
    int n = blockIdx.x, dir = blockIdx.y;
    const float* Wr = dir ? Wr_b : Wr_f;
    __hip_bfloat16* o = WrT + (size_t)dir * G4 * HH + (size_t)n * HH;
    for (int k = threadIdx.x; k < HH; k += 256)
        o[k] = __float2bfloat16(Wr[(size_t)k * G4 + n]);
}

// ---------------------------------------------------------------------------
// Embed GEMM: xz[dir][n][col] = xg @ Wk + b   (bf16 MFMA, frags from L2)
// ---------------------------------------------------------------------------
__global__ __launch_bounds__(256) void embed_gemm(
    const __hip_bfloat16* __restrict__ xg,
    const __hip_bfloat16* __restrict__ WkT,
    const float* __restrict__ b_f, const float* __restrict__ b_b,
    __hip_bfloat16* __restrict__ xz_f, __hip_bfloat16* __restrict__ xz_b)
{
    int dir = blockIdx.z;
    const __hip_bfloat16* wt = WkT + (size_t)dir * G4 * KP;
    const float* bias = dir ? b_b : b_f;
    __hip_bfloat16* xz = dir ? xz_b : xz_f;

    int n0 = blockIdx.x * 64;
    int c0 = blockIdx.y * 64;
    int wave = threadIdx.x >> 6, lane = threadIdx.x & 63;
    int mt2 = (wave & 1) * 2;
    int nt2 = (wave >> 1) * 2;
    int lm = lane & 15, lk8 = (lane >> 4) * 8;

    const short8* ap[2], *bp[2];
    ap[0] = (const short8*)(xg + (size_t)(n0 + (mt2+0)*16 + lm) * KP + lk8);
    ap[1] = (const short8*)(xg + (size_t)(n0 + (mt2+1)*16 + lm) * KP + lk8);
    bp[0] = (const short8*)(wt + (size_t)(c0 + (nt2+0)*16 + lm) * KP + lk8);
    bp[1] = (const short8*)(wt + (size_t)(c0 + (nt2+1)*16 + lm) * KP + lk8);

    floatx4 acc[2][2] = {};
    for (int kc = 0; kc < KP/32; ++kc) {
        short8 a0 = ap[0][kc*4];
        short8 a1 = ap[1][kc*4];
        short8 b0 = bp[0][kc*4];
        short8 b1 = bp[1][kc*4];
        acc[0][0] = __builtin_amdgcn_mfma_f32_16x16x32_bf16(a0, b0, acc[0][0], 0,0,0);
        acc[0][1] = __builtin_amdgcn_mfma_f32_16x16x32_bf16(a0, b1, acc[0][1], 0,0,0);
        acc[1][0] = __builtin_amdgcn_mfma_f32_16x16x32_bf16(a1, b0, acc[1][0], 0,0,0);
        acc[1][1] = __builtin_amdgcn_mfma_f32_16x16x32_bf16(a1, b1, acc[1][1], 0,0,0);
    }

    float bias0 = bias[c0 + (nt2+0)*16 + lm];
    float bias1 = bias[c0 + (nt2+1)*16 + lm];
    int lr = (lane >> 4) * 4;
    #pragma unroll
    for (int mi = 0; mi < 2; ++mi)
        #pragma unroll
        for (int ni = 0; ni < 2; ++ni) {
            int col = c0 + (nt2+ni)*16 + lm;
            float bs = ni ? bias1 : bias0;
            #pragma unroll
            for (int r = 0; r < 4; ++r) {
                int row = n0 + (mt2+mi)*16 + lr + r;
                xz[(size_t)row * G4 + col] = __float2bfloat16(acc[mi][ni][r] + bs);
            }
        }
}

// ---------------------------------------------------------------------------
// Persistent LSTM. 256 blocks (1/CU) x 256 threads, cooperative (co-residency
// for spin barrier). block = (dir, rowgroup16, hgroup16), wave = gate.
// Wr slice in registers all 256 steps. Cross-block h exchange via relaxed
// AGENT-scope atomics (L3 coherence point — NO L2 wbl2/inv fences) + a
// per-group-of-32 one-hop flag barrier.  [replaces 33.8us/step grid.sync()]
// ---------------------------------------------------------------------------
__global__ __launch_bounds__(256, 1) void lstm_coop(
    const __hip_bfloat16* __restrict__ xz_f, const __hip_bfloat16* __restrict__ xz_b,
    const __hip_bfloat16* __restrict__ WrT,   // [2][2048][512]
    __hip_bfloat16* __restrict__ hb,          // [2dir][2par][64][512]
    __hip_bfloat16* __restrict__ hs_f, __hip_bfloat16* __restrict__ hs_b,
    unsigned* __restrict__ flags)             // [8 groups][32]
{
    int blk = blockIdx.x;
    int dir = blk >> 7, sub = blk & 127;
    int r0 = (sub >> 5) * 16;     // 4 rowgroups
    int h0 = (sub & 31) * 16;     // 32 hgroups
    int g  = blk >> 5;            // group id = dir*4 + rowgroup
    int mm = sub & 31;            // member id in group
    int tid = threadIdx.x;
    int gate = tid >> 6, lane = tid & 63;
    int lm = lane & 15, lk8 = (lane >> 4) * 8;

    const __hip_bfloat16* xz = dir ? xz_b : xz_f;
    __hip_bfloat16* hs = dir ? hs_b : hs_f;
    const __hip_bfloat16* wrt = WrT + (size_t)dir * G4 * HH;
    __hip_bfloat16* hbd = hb + (size_t)dir * 2 * BB * HH;
    unsigned* gflags = flags + g * 32;

    // persistent weight fragments (gate's 16 cols x full K=512)
    short8 bfrag[16];
    {
        const short8* wp = (const short8*)(wrt + (size_t)(gate*HH + h0 + lm) * HH + lk8);
        #pragma unroll
        for (int kc = 0; kc < 16; ++kc) bfrag[kc] = wp[kc*4];
    }

    __shared__ unsigned short htile[16][520];   // h(t) rows r0..r0+16, padded
    __shared__ float zbuf[4][16][17];

    // epilogue mapping: threads 0..127 each own (row er, cols ec, ec+1)
    int er = tid >> 3, ec = (tid & 7) * 2;
    float c0st = 0.f, c1st = 0.f;

    for (int t = 0; t < TT; ++t) {
        int tok = dir ? (TT - 1 - t) : t;

        // stage h(t) tile (16x512 bf16 = 2048 u64) into LDS, agent-coherent
        {
            const unsigned long long* src = (const unsigned long long*)
                (hbd + (size_t)(t & 1) * BB * HH + (size_t)r0 * HH);
            #pragma unroll
            for (int i = 0; i < 8; ++i) {
                int idx = tid + i * 256;
                int row = idx >> 7, col4 = idx & 127;
                unsigned long long v = __hip_atomic_load(src + idx,
                    __ATOMIC_RELAXED, __HIP_MEMORY_SCOPE_AGENT);
                *(unsigned long long*)&htile[row][col4 * 4] = v;
            }
        }
        __syncthreads();

        floatx4 acc = {};
        #pragma unroll
        for (int kc = 0; kc < 16; ++kc) {
            short8 a = *(const short8*)&htile[lm][kc * 32 + lk8];
            acc = __builtin_amdgcn_mfma_f32_16x16x32_bf16(a, bfrag[kc], acc, 0,0,0);
        }

        // add xz, publish z-tile to LDS for gate exchange
        #pragma unroll
        for (int r = 0; r < 4; ++r) {
            int row = (lane >> 4) * 4 + r;
            int n = (r0 + row) * TT + tok;
            float z = acc[r] + __bfloat162float(xz[(size_t)n * G4 + gate*HH + h0 + lm]);
            zbuf[gate][row][lm] = z;
        }
        __syncthreads();

        if (tid < 128) {
            float zi0 = zbuf[0][er][ec],   zi1 = zbuf[0][er][ec+1];
            float zf0 = zbuf[1][er][ec],   zf1 = zbuf[1][er][ec+1];
            float zg0 = zbuf[2][er][ec],   zg1 = zbuf[2][er][ec+1];
            float zo0 = zbuf[3][er][ec],   zo1 = zbuf[3][er][ec+1];
            float si0 = 1.f/(1.f+__expf(-zi0)), si1 = 1.f/(1.f+__expf(-zi1));
            float sf0 = 1.f/(1.f+__expf(-zf0)), sf1 = 1.f/(1.f+__expf(-zf1));
            float so0 = 1.f/(1.f+__expf(-zo0)), so1 = 1.f/(1.f+__expf(-zo1));
            c0st = sf0 * c0st + si0 * tanhf(zg0);
            c1st = sf1 * c1st + si1 * tanhf(zg1);
            float h0v = so0 * tanhf(c0st);
            float h1v = so1 * tanhf(c1st);
            unsigned short u0 = __builtin_bit_cast(unsigned short, __float2bfloat16(h0v));
            unsigned short u1 = __builtin_bit_cast(unsigned short, __float2bfloat16(h1v));
            unsigned hv = (unsigned)u0 | ((unsigned)u1 << 16);
            // agent-scope store: visible at coherence point, no fence needed
            __hip_atomic_store((unsigned*)(hbd + (size_t)((t+1) & 1) * BB * HH
                                   + (size_t)(r0 + er) * HH + h0 + ec),
                               hv, __ATOMIC_RELAXED, __HIP_MEMORY_SCOPE_AGENT);
            *(unsigned*)(hs + ((size_t)(r0 + er) * TT + tok) * HH + h0 + ec) = hv;
        }
        __syncthreads();   // drains all waves' stores (pre-barrier vmcnt(0))

        if (t < TT - 1) {
            __atomic_signal_fence(__ATOMIC_ACQ_REL);
            if (tid == 0)
                __hip_atomic_store(&gflags[mm], (unsigned)(t + 1),
                                   __ATOMIC_RELAXED, __HIP_MEMORY_SCOPE_AGENT);
            unsigned tgt = (unsigned)(t + 1);
            const unsigned* fp = &gflags[lane & 31];
            while (__hip_atomic_load(fp, __ATOMIC_RELAXED,
                                     __HIP_MEMORY_SCOPE_AGENT) < tgt) {}
            __atomic_signal_fence(__ATOMIC_ACQ_REL);
        }
    }
}

// ---------------------------------------------------------------------------
// logits = [hf, hb] @ Wd + bd
// ---------------------------------------------------------------------------
__global__ __launch_bounds__(64) void logits_kernel(
    const __hip_bfloat16* __restrict__ hs_f, const __hip_bfloat16* __restrict__ hs_b,
    const float* __restrict__ Wd, const float* __restrict__ bd,
    float* __restrict__ out)
{
    int n = blockIdx.x;
    int tid = threadIdx.x;
    __shared__ float red[64][10];
    float acc[LL] = {};
    for (int kk = 0; kk < 16; ++kk) {
        int k = kk * 64 + tid;
        float hv = (k < HH) ? __bfloat162float(hs_f[(size_t)n * HH + k])
                            : __bfloat162float(hs_b[(size_t)n * HH + (k - HH)]);
        const float* w = Wd + (size_t)k * LL;
        #pragma unroll
        for (int l = 0; l < LL; ++l) acc[l] += hv * w[l];
    }
    #pragma unroll
    for (int l = 0; l < LL; ++l) red[tid][l] = acc[l];
    __syncthreads();
    for (int s = 32; s > 0; s >>= 1) {
        if (tid < s)
            for (int l = 0; l < LL; ++l) red[tid][l] += red[tid + s][l];
        __syncthreads();
    }
    if (tid < LL) out[(size_t)n * LL + tid] = red[0][tid] + bd[tid];
}

// ---------------------------------------------------------------------------
// text lengths
// ---------------------------------------------------------------------------
__global__ __launch_bounds__(256) void lens_kernel(
    const int* __restrict__ text, float* __restrict__ out_lens, int* __restrict__ len_i)
{
    int b = blockIdx.x, tid = threadIdx.x;
    __shared__ int sred[256];
    sred[tid] = (text[b * TT + tid] != 0) ? 1 : 0;
    __syncthreads();
    for (int s = 128; s > 0; s >>= 1) {
        if (tid < s) sred[tid] += sred[tid + s];
        __syncthreads();
    }
    if (tid == 0) { out_lens[b] = (float)sred[0]; len_i[b] = sred[0]; }
}

// ---------------------------------------------------------------------------
// CRF log-likelihood + Viterbi decode (one block per batch item)
// ---------------------------------------------------------------------------
__global__ __launch_bounds__(128) void crf_kernel(
    const float* __restrict__ logits, const int* __restrict__ labels,
    const float* __restrict__ trans, const int* __restrict__ len_i,
    int* __restrict__ bp, float* __restrict__ out_ll, float* __restrict__ out_tags)
{
    int b = blockIdx.x, tid = threadIdx.x;
    int len = len_i[b];
    const float* lg = logits + (size_t)b * TT * LL;
    const int* lab = labels + b * TT;

    __shared__ float tr[81];
    __shared__ float alpha[LL], vit[LL], newa[LL], newv[LL];
    __shared__ int newbp[LL];
    __shared__ float partial[128];

    if (tid < 81) tr[tid] = trans[tid];
    if (tid < LL) { alpha[tid] = lg[tid]; vit[tid] = lg[tid]; }
    __syncthreads();

    float up = 0.f;
    for (int t = tid; t < TT; t += 128) {
        float m = (t < len) ? 1.f : 0.f;
        up += m * lg[t * LL + lab[t]];
        if (t >= 1) up += m * tr[lab[t - 1] * LL + lab[t]];
    }
    partial[tid] = up;
    __syncthreads();
    for (int s = 64; s > 0; s >>= 1) {
        if (tid < s) partial[tid] += partial[tid + s];
        __syncthreads();
    }

    for (int t = 1; t < TT; ++t) {
        bool m = t < len;
        if (tid < LL) {
            int j = tid;
            float mx = -1e30f;
            #pragma unroll
            for (int i = 0; i < LL; ++i) mx = fmaxf(mx, alpha[i] + tr[i * LL + j]);
            float s = 0.f;
            #pragma unroll
            for (int i = 0; i < LL; ++i) s += __expf(alpha[i] + tr[i * LL + j] - mx);
            newa[j] = mx + __logf(s) + lg[t * LL + j];
        } else if (tid >= 64 && tid < 64 + LL) {
            int j = tid - 64;
            float best = -1e30f; int bi = 0;
            #pragma unroll
            for (int i = 0; i < LL; ++i) {
                float sc = vit[i] + tr[i * LL + j];
                if (sc > best) { best = sc; bi = i; }
            }
            newv[j] = best + lg[t * LL + j];
            newbp[j] = bi;
        }
        __syncthreads();
        if (tid < LL) {
            if (m) alpha[tid] = newa[tid];
        } else if (tid >= 64 && tid < 64 + LL) {
            int j = tid - 64;
            if (m) vit[j] = newv[j];
            bp[((size_t)b * (TT - 1) + (t - 1)) * LL + j] = m ? newbp[j] : j;
        }
        __syncthreads();
    }

    if (tid == 0) {
        float mx = -1e30f;
        #pragma unroll
        for (int j = 0; j < LL; ++j) mx = fmaxf(mx, alpha[j]);
        float s = 0.f;
        #pragma unroll
        for (int j = 0; j < LL; ++j) s += __expf(alpha[j] - mx);
        out_ll[b] = partial[0] - (mx + __logf(s));

        float bv = vit[0]; int last = 0;
        #pragma unroll
        for (int j = 1; j < LL; ++j) if (vit[j] > bv) { bv = vit[j]; last = j; }
        out_tags[b * TT + (TT - 1)] = (float)last;
        int tag = last;
        for (int s2 = TT - 2; s2 >= 0; --s2) {
            tag = bp[((size_t)b * (TT - 1) + s2) * LL + tag];
            out_tags[b * TT + s2] = (float)tag;
        }
    }
}

// ---------------------------------------------------------------------------
extern "C" void kernel_launch(void* const* d_in, const int* in_sizes, int n_in,
                              void* d_out, int out_size, void* d_ws, size_t ws_size,
                              hipStream_t stream)
{
    const int*   text  = (const int*)d_in[0];
    const int*   sent  = (const int*)d_in[1];
    const int*   labels= (const int*)d_in[2];
    const float* wemb  = (const float*)d_in[3];
    const float* semb  = (const float*)d_in[4];
    const float* Wk_f  = (const float*)d_in[5];
    const float* Wr_f  = (const float*)d_in[6];
    const float* b_f   = (const float*)d_in[7];
    const float* Wk_b  = (const float*)d_in[8];
    const float* Wr_b  = (const float*)d_in[9];
    const float* b_b   = (const float*)d_in[10];
    const float* Wd    = (const float*)d_in[11];
    const float* bd    = (const float*)d_in[12];
    const float* trans = (const float*)d_in[13];
    float* out = (float*)d_out;

    char* ws = (char*)d_ws;
    __hip_bfloat16* xz_f = (__hip_bfloat16*)(ws + XZF_OFF);
    __hip_bfloat16* xz_b = (__hip_bfloat16*)(ws + XZB_OFF);
    __hip_bfloat16* hs_f = (__hip_bfloat16*)(ws + HSF_OFF);
    __hip_bfloat16* hs_b = (__hip_bfloat16*)(ws + HSB_OFF);
    __hip_bfloat16* xg   = (__hip_bfloat16*)(ws + XG_OFF);
    __hip_bfloat16* WkT  = (__hip_bfloat16*)(ws + WKT_OFF);
    __hip_bfloat16* WrT  = (__hip_bfloat16*)(ws + WRT_OFF);
    __hip_bfloat16* hb   = (__hip_bfloat16*)(ws + HB_OFF);
    int*      bp    = (int*)(ws + BP_OFF);
    int*      leni  = (int*)(ws + LEN_OFF);
    unsigned* flags = (unsigned*)(ws + FLAGS_OFF);

    prep_xg <<<NT,  256, 0, stream>>>(text, sent, wemb, semb, xg);
    prep_wkT<<<dim3(G4, 2), 256, 0, stream>>>(Wk_f, Wk_b, WkT);
    prep_wrT<<<dim3(G4, 2), 256, 0, stream>>>(Wr_f, Wr_b, WrT);
    // zero h ping-pong + len + flags (contiguous region)
    hipMemsetAsync(ws + HB_OFF, 0, HB_BYTES + 256 + 1024, stream);

    embed_gemm<<<dim3(NT/64, G4/64, 2), 256, 0, stream>>>(
        xg, WkT, b_f, b_b, xz_f, xz_b);

    {
        void* args[] = { (void*)&xz_f, (void*)&xz_b, (void*)&WrT,
                         (void*)&hb, (void*)&hs_f, (void*)&hs_b, (void*)&flags };
        hipLaunchCooperativeKernel((const void*)lstm_coop, dim3(256), dim3(256),
                                   args, 0, stream);
    }

    logits_kernel<<<NT, 64, 0, stream>>>(hs_f, hs_b, Wd, bd, out + OUT_LOGITS);
    lens_kernel<<<BB, 256, 0, stream>>>(text, out + OUT_LENS, leni);
    crf_kernel<<<BB, 128, 0, stream>>>(out + OUT_LOGITS, labels, trans, leni,
                                       bp, out + OUT_LL, out + OUT_TAGS);
}